// Round 3
// baseline (158.894 us; speedup 1.0000x reference)
//
#include <hip/hip_runtime.h>

constexpr int IN_F   = 32;
constexpr int OUT_F  = 128;
constexpr int BLOCK  = 256;
constexpr int WAVES  = BLOCK / 64;
constexpr int RSTAGE = 16;         // rows staged per wave per iteration

using f32x2 = __attribute__((ext_vector_type(2))) float;

__global__ __launch_bounds__(BLOCK, 4)
void rbf_kernel(const float* __restrict__ x,
                const float* __restrict__ centres,
                const float* __restrict__ log_sigmas,
                float* __restrict__ out,
                int rows_per_wave)
{
    // double-buffered, wave-private x slab: 2 KB/buffer/wave
    __shared__ float4 xs[WAVES][2][RSTAGE][IN_F / 4];

    const int tid  = threadIdx.x;
    const int wv   = tid >> 6;
    const int lane = tid & 63;

    // ---- per-lane centres (outputs 2*lane, 2*lane+1) in registers ----
    const int o0 = lane * 2;
    float c0[IN_F], c1[IN_F];
    float c2a = 0.f, c2b = 0.f;
    #pragma unroll
    for (int kc = 0; kc < IN_F / 4; ++kc) {
        const float4 a = *reinterpret_cast<const float4*>(centres + (size_t)(o0 + 0) * IN_F + kc * 4);
        const float4 b = *reinterpret_cast<const float4*>(centres + (size_t)(o0 + 1) * IN_F + kc * 4);
        c0[kc*4+0] = a.x; c0[kc*4+1] = a.y; c0[kc*4+2] = a.z; c0[kc*4+3] = a.w;
        c1[kc*4+0] = b.x; c1[kc*4+1] = b.y; c1[kc*4+2] = b.z; c1[kc*4+3] = b.w;
        c2a = fmaf(a.x,a.x,c2a); c2a = fmaf(a.y,a.y,c2a);
        c2a = fmaf(a.z,a.z,c2a); c2a = fmaf(a.w,a.w,c2a);
        c2b = fmaf(b.x,b.x,c2b); c2b = fmaf(b.y,b.y,c2b);
        c2b = fmaf(b.z,b.z,c2b); c2b = fmaf(b.w,b.w,c2b);
    }
    const float iv0 = __expf(-2.0f * log_sigmas[o0 + 0]);
    const float iv1 = __expf(-2.0f * log_sigmas[o0 + 1]);

    const size_t waveRow0 = ((size_t)blockIdx.x * WAVES + wv) * (size_t)rows_per_wave;
    const float* xbase = x + waveRow0 * IN_F;
    const int rs = lane >> 3;      // row (within 8-row half) this lane loads
    const int q  = lane & 7;       // float4 slot within that row

    // ---- prologue: prefetch first 16 rows (2 coalesced 1 KB loads) ----
    float4 va = *reinterpret_cast<const float4*>(xbase + lane * 4);              // rows 0..7
    float4 vb = *reinterpret_cast<const float4*>(xbase + 8 * IN_F + lane * 4);   // rows 8..15

    int buf = 0;
    for (int it = 0; it < rows_per_wave; it += RSTAGE) {
        // ---- ||x||^2 for the staged rows (kept in regs, shfl-broadcast) ----
        float sa = va.x * va.x;
        sa = fmaf(va.y, va.y, sa); sa = fmaf(va.z, va.z, sa); sa = fmaf(va.w, va.w, sa);
        sa += __shfl_xor(sa, 1); sa += __shfl_xor(sa, 2); sa += __shfl_xor(sa, 4);
        float sb = vb.x * vb.x;
        sb = fmaf(vb.y, vb.y, sb); sb = fmaf(vb.z, vb.z, sb); sb = fmaf(vb.w, vb.w, sb);
        sb += __shfl_xor(sb, 1); sb += __shfl_xor(sb, 2); sb += __shfl_xor(sb, 4);

        xs[wv][buf][rs][q]     = va;
        xs[wv][buf][8 + rs][q] = vb;

        // ---- issue next stage's loads NOW (stay in flight under compute;
        //      lgkmcnt wait below does not drain vmcnt) ----
        if (it + RSTAGE < rows_per_wave) {
            const float* nxt = xbase + (size_t)(it + RSTAGE) * IN_F;
            va = *reinterpret_cast<const float4*>(nxt + lane * 4);
            vb = *reinterpret_cast<const float4*>(nxt + 8 * IN_F + lane * 4);
        }

        // wave-private exchange: all 64 lanes' ds_writes complete (per-wave counter)
        asm volatile("s_waitcnt lgkmcnt(0)" ::: "memory");

        #pragma unroll
        for (int rr = 0; rr < RSTAGE; ++rr) {
            float acc0 = 0.f, acc1 = 0.f;
            #pragma unroll
            for (int kc = 0; kc < IN_F / 4; ++kc) {
                const float4 xk = xs[wv][buf][rr][kc];   // wave-uniform: broadcast
                acc0 = fmaf(xk.x, c0[kc*4+0], acc0);
                acc0 = fmaf(xk.y, c0[kc*4+1], acc0);
                acc0 = fmaf(xk.z, c0[kc*4+2], acc0);
                acc0 = fmaf(xk.w, c0[kc*4+3], acc0);
                acc1 = fmaf(xk.x, c1[kc*4+0], acc1);
                acc1 = fmaf(xk.y, c1[kc*4+1], acc1);
                acc1 = fmaf(xk.z, c1[kc*4+2], acc1);
                acc1 = fmaf(xk.w, c1[kc*4+3], acc1);
            }
            const float x2 = (rr < 8) ? __shfl(sa, rr * 8) : __shfl(sb, (rr - 8) * 8);
            const float t0 = fmaxf(fmaf(-2.0f, acc0, x2 + c2a), 0.0f);
            const float t1 = fmaxf(fmaf(-2.0f, acc1, x2 + c2b), 0.0f);
            f32x2 o;
            o.x = __expf(-t0 * iv0);
            o.y = __expf(-t1 * iv1);
            // lane l writes bytes [8l, 8l+8) of the row: 512 B contiguous/wave
            __builtin_nontemporal_store(o,
                reinterpret_cast<f32x2*>(out + (waveRow0 + it + rr) * OUT_F + o0));
        }
        buf ^= 1;
    }
}

extern "C" void kernel_launch(void* const* d_in, const int* in_sizes, int n_in,
                              void* d_out, int out_size, void* d_ws, size_t ws_size,
                              hipStream_t stream) {
    const float* x          = (const float*)d_in[0];
    const float* centres    = (const float*)d_in[1];
    const float* log_sigmas = (const float*)d_in[2];
    float* out = (float*)d_out;

    const int n = in_sizes[0] / IN_F;                   // 1,048,576 rows
    const int blocks = 2048;
    const int rows_per_block = n / blocks;              // 512
    const int rows_per_wave  = rows_per_block / WAVES;  // 128 (8 stages of 16)
    rbf_kernel<<<blocks, BLOCK, 0, stream>>>(x, centres, log_sigmas, out, rows_per_wave);
}